// Round 4
// baseline (786.128 us; speedup 1.0000x reference)
//
#include <hip/hip_runtime.h>
#include <cmath>

#define BB 256
#define TT 512
#define NN 128
#define LN2F 0.6931471805599453f

__device__ __forceinline__ float wave_max64(float v) {
    #pragma unroll
    for (int off = 32; off; off >>= 1) v = fmaxf(v, __shfl_xor(v, off));
    return v;
}
__device__ __forceinline__ float wave_sum64(float v) {
    #pragma unroll
    for (int off = 32; off; off >>= 1) v += __shfl_xor(v, off);
    return v;
}
__device__ __forceinline__ int wave_argmax128(float v0, float v1, int l) {
    float m = fmaxf(v0, v1);
    float wm = wave_max64(m);
    unsigned long long ball = __ballot(m == wm);
    int lane = __ffsll(ball) - 1;
    int idx = (v0 == wm) ? (2 * l) : (2 * l + 1);
    return __shfl(idx, lane);
}

// Padded state layout: 32-float chunk c starts at word 36c (bank offset 4c).
__device__ __forceinline__ int padidx(int i) { return 36 * (i >> 5) + (i & 31); }

// Forward, grid = 2*BB. Even blocks: Viterbi chain. Odd blocks: log-norm chain.
// 256 threads = 4 waves. Thread handles columns j1=(l&15)+16w and j2=j1+64 over
// i-chunk q=l>>4 (32 i's): one 128 B LDS read serves 64 MACs. Combine via
// shfl_xor(16/32); lanes l<16 hold finals and own the per-column state.
__global__ __launch_bounds__(256, 2) void fwd_kernel(
        const float* __restrict__ em, const int* __restrict__ mask,
        const float* __restrict__ trans, float* __restrict__ bhist,
        float* __restrict__ lognorm) {
    const int bi = blockIdx.x;
    const int b = bi >> 1;
    const bool isV = (bi & 1) == 0;
    const int tid = threadIdx.x;
    const int w = tid >> 6;
    const int l = tid & 63;
    const int j1 = (l & 15) + 16 * w;
    const int j2 = j1 + 64;
    const int q = l >> 4;
    const int i0 = 32 * q;

    float C1[32], C2[32];
    {
        const float* tc = trans + (size_t)i0 * NN;
        #pragma unroll
        for (int r = 0; r < 32; ++r) {
            C1[r] = tc[(size_t)r * NN + j1];
            C2[r] = tc[(size_t)r * NN + j2];
        }
        if (!isV) {
            #pragma unroll
            for (int r = 0; r < 32; ++r) { C1[r] = __expf(C1[r]); C2[r] = __expf(C2[r]); }
        }
    }

    __shared__ __align__(16) float apad[2][144];   // alpha (V) or s (L)
    __shared__ __align__(16) float ring[32 * NN];  // V only: bestpre ring, 16 KB
    __shared__ int msk[TT];
    __shared__ float piv[2];
    __shared__ float sfin[NN];

    msk[tid] = mask[b * TT + tid];
    msk[tid + 256] = mask[b * TT + 256 + tid];

    const float* emb = em + (size_t)b * TT * NN;
    float* bh = bhist + (size_t)b * TT * NN;

    float st1 = 0.f, st2 = 0.f;  // writer-lane per-column state
    int kacc = 0;
    if (l < 16) {
        float a1 = emb[j1], a2 = emb[j2];
        if (isV) {
            st1 = a1; st2 = a2;
            apad[0][padidx(j1)] = a1; apad[0][padidx(j2)] = a2;
            ring[j1] = a1; ring[j2] = a2;   // row 0 = alpha0 itself
        } else {
            st1 = __expf(a1); st2 = __expf(a2);
            apad[0][padidx(j1)] = st1; apad[0][padidx(j2)] = st2;
            if (tid == 0) piv[0] = st1;
        }
    }
    float e1n = 0.f, e2n = 0.f;
    if (l < 16) { e1n = emb[NN + j1]; e2n = emb[NN + j2]; }
    __syncthreads();

    for (int t = 1; t < TT; ++t) {
        if (isV && (t & 15) == 0) {  // flush 16 ring rows (disjoint slots)
            const int sbase = ((t - 16) & 31) * NN + tid * 8;
            float4 w0 = *(const float4*)(ring + sbase);
            float4 w1 = *(const float4*)(ring + sbase + 4);
            float* dst = bh + (size_t)(t - 16) * NN + tid * 8;
            *(float4*)dst = w0;
            *(float4*)(dst + 4) = w1;
        }
        const float e1 = e1n, e2 = e2n;
        if (l < 16 && t + 1 < TT) {
            e1n = emb[(size_t)(t + 1) * NN + j1];
            e2n = emb[(size_t)(t + 1) * NN + j2];
        }
        const int m = msk[t];
        const int p = (t - 1) & 1, qb = t & 1;

        if (isV) {
            const float4* ap = (const float4*)(apad[p] + 36 * q);
            float x1 = -INFINITY, y1 = -INFINITY, x2 = -INFINITY, y2 = -INFINITY;
            #pragma unroll
            for (int u = 0; u < 8; ++u) {
                float4 v = ap[u];
                x1 = fmaxf(fmaxf(x1, v.x + C1[4*u+0]), v.y + C1[4*u+1]);
                y1 = fmaxf(fmaxf(y1, v.z + C1[4*u+2]), v.w + C1[4*u+3]);
                x2 = fmaxf(fmaxf(x2, v.x + C2[4*u+0]), v.y + C2[4*u+1]);
                y2 = fmaxf(fmaxf(y2, v.z + C2[4*u+2]), v.w + C2[4*u+3]);
            }
            float b1 = fmaxf(x1, y1), b2 = fmaxf(x2, y2);
            b1 = fmaxf(b1, __shfl_xor(b1, 16)); b1 = fmaxf(b1, __shfl_xor(b1, 32));
            b2 = fmaxf(b2, __shfl_xor(b2, 16)); b2 = fmaxf(b2, __shfl_xor(b2, 32));
            if (l < 16) {
                float n1, n2, s1, s2;
                if (m) { n1 = b1 + e1; s1 = b1; n2 = b2 + e2; s2 = b2; }  // exact add
                else   { n1 = st1;     s1 = st1; n2 = st2;    s2 = st2; }
                st1 = n1; st2 = n2;
                apad[qb][padidx(j1)] = n1; apad[qb][padidx(j2)] = n2;
                ring[(t & 31) * NN + j1] = s1; ring[(t & 31) * NN + j2] = s2;
            }
        } else {
            const float pv = piv[p];
            const float4* sp = (const float4*)(apad[p] + 36 * q);
            float d1 = 0, g1 = 0, d2 = 0, g2 = 0;
            #pragma unroll
            for (int u = 0; u < 8; ++u) {
                float4 v = sp[u];
                d1 = fmaf(v.x, C1[4*u+0], d1); g1 = fmaf(v.y, C1[4*u+1], g1);
                d1 = fmaf(v.z, C1[4*u+2], d1); g1 = fmaf(v.w, C1[4*u+3], g1);
                d2 = fmaf(v.x, C2[4*u+0], d2); g2 = fmaf(v.y, C2[4*u+1], g2);
                d2 = fmaf(v.z, C2[4*u+2], d2); g2 = fmaf(v.w, C2[4*u+3], g2);
            }
            float o1 = d1 + g1, o2 = d2 + g2;
            o1 += __shfl_xor(o1, 16); o1 += __shfl_xor(o1, 32);
            o2 += __shfl_xor(o2, 16); o2 += __shfl_xor(o2, 32);
            const int k = (int)(__float_as_uint(pv) >> 23) - 127;
            const float scale = __uint_as_float((unsigned)(127 - k) << 23);  // 2^-k
            if (m) kacc += k;
            if (l < 16) {
                float n1 = m ? o1 * scale * __expf(e1) : st1;
                float n2 = m ? o2 * scale * __expf(e2) : st2;
                st1 = n1; st2 = n2;
                apad[qb][padidx(j1)] = n1; apad[qb][padidx(j2)] = n2;
                if (tid == 0) piv[qb] = n1;   // column 0 pivot
            }
        }
        __syncthreads();
    }

    if (isV) {  // tail: rows 496..511 in slots 16..31
        float4 w0 = *(const float4*)(ring + 16 * NN + tid * 8);
        float4 w1 = *(const float4*)(ring + 16 * NN + tid * 8 + 4);
        float* dst = bh + (size_t)496 * NN + tid * 8;
        *(float4*)dst = w0;
        *(float4*)(dst + 4) = w1;
    } else {
        if (l < 16) { sfin[j1] = st1; sfin[j2] = st2; }
        __syncthreads();
        if (tid < 64) {
            float v = sfin[2 * tid] + sfin[2 * tid + 1];
            v = wave_sum64(v);
            if (tid == 0) lognorm[b] = __logf(v) + (float)kacc * LN2F;
        }
    }
}

// Backward: equality search against stored bestpre, depth-4 prefetch pipeline.
// alpha[r] = bh[r] + (r>0 && msk[r] ? em[r] : 0)   (bitwise == fwd).
__global__ __launch_bounds__(64, 1) void bwd_kernel(
        const float* __restrict__ bhist, const float* __restrict__ em,
        const int* __restrict__ mask, const float* __restrict__ trans,
        float* __restrict__ outp) {
    const int b = blockIdx.x;
    const int l = threadIdx.x;

    __shared__ float Tt[NN * 129];
    __shared__ int msk[TT];
    #pragma unroll 4
    for (int it = 0; it < 256; ++it) {
        int idx = it * 64 + l;
        Tt[(idx & 127) * 129 + (idx >> 7)] = trans[idx];
    }
    for (int i = l; i < TT; i += 64) msk[i] = mask[b * TT + i];

    const float* bhp = bhist + (size_t)b * TT * NN;
    const float* emp = em + (size_t)b * TT * NN;
    float* op = outp + (size_t)b * TT;
    __syncthreads();

    #define LDROW(r) (*(const float2*)(bhp + (size_t)(r) * NN + 2 * l))
    #define LDEM(r)  (*(const float2*)(emp + (size_t)(r) * NN + 2 * l))

    float2 r511 = LDROW(511), e511 = LDEM(511);
    float2 ba = LDROW(510), ea = LDEM(510);
    float2 bb = LDROW(509), eb = LDEM(509);
    float2 bc = LDROW(508), ec = LDEM(508);
    float2 bd = LDROW(507), ed = LDEM(507);

    float a0 = r511.x + (msk[511] ? e511.x : 0.f);
    float a1 = r511.y + (msk[511] ? e511.y : 0.f);
    int tag = wave_argmax128(a0, a1, l);
    if (l == 0) op[TT - 1] = (float)tag;
    float bt0 = r511.x, bt1 = r511.y;

    for (int t = TT - 1; t >= 1; --t) {
        const int rm = (t - 1 > 0) && msk[t - 1];
        float al0 = ba.x + (rm ? ea.x : 0.f);
        float al1 = ba.y + (rm ? ea.y : 0.f);
        if (msk[t]) {
            float wsrc = (tag & 1) ? bt1 : bt0;
            float W = __shfl(wsrc, tag >> 1);
            float c0 = al0 + Tt[tag * 129 + 2 * l];
            float c1 = al1 + Tt[tag * 129 + 2 * l + 1];
            unsigned long long m0 = __ballot(c0 == W);
            unsigned long long m1 = __ballot(c1 == W);
            int i0 = m0 ? 2 * (__ffsll(m0) - 1) : (1 << 30);
            int i1 = m1 ? 2 * (__ffsll(m1) - 1) + 1 : (1 << 30);
            int nt = min(i0, i1);
            if (nt < NN) tag = nt;
        }
        if (l == 0) op[t - 1] = (float)tag;
        bt0 = ba.x; bt1 = ba.y;
        ba = bb; ea = eb;
        bb = bc; eb = ec;
        bc = bd; ec = ed;
        int r = t - 5; if (r < 0) r = 0;
        bd = LDROW(r); ed = LDEM(r);
    }
    #undef LDROW
    #undef LDEM
}

__global__ __launch_bounds__(128, 1) void score_kernel(
        const float* __restrict__ em, const int* __restrict__ tags,
        const int* __restrict__ mask, const float* __restrict__ trans,
        const float* __restrict__ lognorm, float* __restrict__ out_ll) {
    const int b = blockIdx.x;
    const int tid = threadIdx.x;
    float acc = 0.f;
    for (int t = tid; t < TT; t += 128) {
        int tg = tags[b * TT + t];
        float mf = (float)mask[b * TT + t];
        acc += em[((size_t)b * TT + t) * NN + tg] * mf;
        if (t >= 1) {
            int tp = tags[b * TT + t - 1];
            acc += trans[tp * NN + tg] * mf;
        }
    }
    acc = wave_sum64(acc);
    __shared__ float rs[2];
    if ((tid & 63) == 0) rs[tid >> 6] = acc;
    __syncthreads();
    if (tid == 0) out_ll[b] = (rs[0] + rs[1]) - lognorm[b];
}

__global__ void copy_trans_kernel(const float* __restrict__ trans,
                                  float* __restrict__ dst) {
    int i = blockIdx.x * 256 + threadIdx.x;
    if (i < NN * NN) dst[i] = trans[i];
}

extern "C" void kernel_launch(void* const* d_in, const int* in_sizes, int n_in,
                              void* d_out, int out_size, void* d_ws, size_t ws_size,
                              hipStream_t stream) {
    const float* em = (const float*)d_in[0];
    const int* tags = (const int*)d_in[1];
    const int* mask = (const int*)d_in[2];
    const float* trans = (const float*)d_in[3];

    float* out = (float*)d_out;
    float* out_ll = out;
    float* out_trans = out + BB;
    float* out_pred = out + BB + NN * NN;

    float* bhist = (float*)d_ws;                    // B*T*N fp32 = 64 MB
    float* lognorm = bhist + (size_t)BB * TT * NN;  // [256]

    hipLaunchKernelGGL(fwd_kernel, dim3(2 * BB), dim3(256), 0, stream,
                       em, mask, trans, bhist, lognorm);
    hipLaunchKernelGGL(copy_trans_kernel, dim3(64), dim3(256), 0, stream,
                       trans, out_trans);
    hipLaunchKernelGGL(score_kernel, dim3(BB), dim3(128), 0, stream,
                       em, tags, mask, trans, lognorm, out_ll);
    hipLaunchKernelGGL(bwd_kernel, dim3(BB), dim3(64), 0, stream,
                       bhist, em, mask, trans, out_pred);
}

// Round 5
// 585.234 us; speedup vs baseline: 1.3433x; 1.3433x over previous
//
#include <hip/hip_runtime.h>
#include <cmath>

#define BB 256
#define TT 512
#define NN 128
#define LN2F 0.6931471805599453f

__device__ __forceinline__ float wave_max64(float v) {
    #pragma unroll
    for (int off = 32; off; off >>= 1) v = fmaxf(v, __shfl_xor(v, off));
    return v;
}
__device__ __forceinline__ float wave_sum64(float v) {
    #pragma unroll
    for (int off = 32; off; off >>= 1) v += __shfl_xor(v, off);
    return v;
}
// argmax over 128 values (lane l holds indices 2l, 2l+1); first-index tie-break.
__device__ __forceinline__ int wave_argmax128(float v0, float v1, int l) {
    float m = fmaxf(v0, v1);
    float wm = wave_max64(m);
    unsigned long long ball = __ballot(m == wm);
    int lane = __ffsll(ball) - 1;
    int idx = (v0 == wm) ? (2 * l) : (2 * l + 1);
    return __shfl(idx, lane);
}

// Padded state layout: 32-float chunk c starts at word 36c (bank offset 4c).
__device__ __forceinline__ int padidx(int i) { return 36 * (i >> 5) + (i & 31); }

// Forward: 1024 threads/batch (round-3 structure), fused Viterbi-with-backpointers
// + log-norm + in-block backtrace. No global history.
//   waves 0-7: Viterbi (argmax-tracked). waves 8-15: log-norm (linear, col-0 pivot).
//   j = (l&15) + 16*(w&7), i-chunk q = l>>4. Combine via shfl_xor(16/32).
//   bp[t][j] u8 in LDS (64 KB); single-lane backtrace at the end.
__global__ __launch_bounds__(1024, 4) void fwd_kernel(
        const float* __restrict__ em, const int* __restrict__ mask,
        const float* __restrict__ trans, float* __restrict__ outp,
        float* __restrict__ lognorm) {
    const int b = blockIdx.x;
    const int tid = threadIdx.x;
    const int w = tid >> 6;
    const int l = tid & 63;
    const bool isV = (w < 8);
    const int wl = w & 7;
    const int j = (l & 15) + 16 * wl;
    const int q = l >> 4;
    const int i0 = 32 * q;

    float C[32];  // trans[i0+r][j]  (log waves: exp of it)
    {
        const float* tc = trans + (size_t)i0 * NN + j;
        #pragma unroll
        for (int r = 0; r < 32; ++r) C[r] = tc[(size_t)r * NN];
        if (!isV) {
            #pragma unroll
            for (int r = 0; r < 32; ++r) C[r] = __expf(C[r]);
        }
    }

    __shared__ __align__(16) float apad[2][144];     // viterbi alpha
    __shared__ __align__(16) float spad[2][144];     // log-norm linear state
    __shared__ unsigned char bp_lds[TT * NN];        // backpointers, 64 KB
    __shared__ unsigned char tags_lds[TT];
    __shared__ int msk[TT];
    __shared__ float piv[2];
    __shared__ float sfin[NN];
    __shared__ int kacc_sh;

    if (tid < TT) msk[tid] = mask[b * TT + tid];

    const float* emb = em + (size_t)b * TT * NN;

    float e0 = emb[j];
    float st = 0.f;     // writer-lane state (alpha for V, s for L)
    int kacc = 0;
    if (isV) {
        st = e0;
        if (l < 16) apad[0][padidx(j)] = st;
    } else {
        st = __expf(e0);
        if (l < 16) spad[0][padidx(j)] = st;
        if (w == 8 && l == 0) piv[0] = st;
    }
    float e_next = emb[NN + j];
    __syncthreads();

    for (int t = 1; t < TT; ++t) {
        const float e_cur = e_next;
        if (t + 1 < TT) e_next = emb[(size_t)(t + 1) * NN + j];
        const int m = msk[t];
        const int p = (t - 1) & 1, qb = t & 1;

        if (isV) {
            const float4* ap = (const float4*)(apad[p] + 36 * q);
            float m0 = -INFINITY, m1 = -INFINITY, m2 = -INFINITY, m3 = -INFINITY;
            int u0 = 0, u1 = 0, u2 = 0, u3 = 0;
            #pragma unroll
            for (int u = 0; u < 8; ++u) {
                float4 v = ap[u];
                float c0 = v.x + C[4*u+0];
                float c1 = v.y + C[4*u+1];
                float c2 = v.z + C[4*u+2];
                float c3 = v.w + C[4*u+3];
                if (c0 > m0) { m0 = c0; u0 = u; }   // strict >: first-index per residue
                if (c1 > m1) { m1 = c1; u1 = u; }
                if (c2 > m2) { m2 = c2; u2 = u; }
                if (c3 > m3) { m3 = c3; u3 = u; }
            }
            float bv = m0; int bi = i0 + 4 * u0;
            { int id = i0 + 4*u1 + 1; if (m1 > bv || (m1 == bv && id < bi)) { bv = m1; bi = id; } }
            { int id = i0 + 4*u2 + 2; if (m2 > bv || (m2 == bv && id < bi)) { bv = m2; bi = id; } }
            { int id = i0 + 4*u3 + 3; if (m3 > bv || (m3 == bv && id < bi)) { bv = m3; bi = id; } }
            #pragma unroll
            for (int off = 16; off <= 32; off <<= 1) {
                float ov = __shfl_xor(bv, off);
                int oi = __shfl_xor(bi, off);
                if (ov > bv || (ov == bv && oi < bi)) { bv = ov; bi = oi; }
            }
            if (l < 16) {
                float av_new; int bp;
                if (m) { av_new = bv + e_cur; bp = bi; }  // plain add = reference
                else   { av_new = st;         bp = j;  }  // identity bp when masked
                st = av_new;
                apad[qb][padidx(j)] = av_new;
                bp_lds[t * NN + j] = (unsigned char)bp;
            }
        } else {
            const float pv = piv[p];
            const float4* sp = (const float4*)(spad[p] + 36 * q);
            float d0 = 0, d1 = 0, d2 = 0, d3 = 0;
            #pragma unroll
            for (int u = 0; u < 8; ++u) {
                float4 v = sp[u];
                d0 = fmaf(v.x, C[4*u+0], d0);
                d1 = fmaf(v.y, C[4*u+1], d1);
                d2 = fmaf(v.z, C[4*u+2], d2);
                d3 = fmaf(v.w, C[4*u+3], d3);
            }
            float dot = (d0 + d1) + (d2 + d3);
            dot += __shfl_xor(dot, 16);
            dot += __shfl_xor(dot, 32);
            const int k = (int)(__float_as_uint(pv) >> 23) - 127;
            const float scale = __uint_as_float((unsigned)(127 - k) << 23);  // 2^-k
            float s_new;
            if (m) { s_new = dot * scale * __expf(e_cur); kacc += k; }
            else   { s_new = st; }
            st = s_new;
            if (l < 16) {
                spad[qb][padidx(j)] = s_new;
                if (tid == 512 + 0 && false) {}
            }
            if (w == 8 && l == 0) piv[qb] = s_new;
        }
        __syncthreads();
    }

    if (!isV && l < 16) sfin[j] = st;
    if (w == 8 && l == 0) kacc_sh = kacc;
    __syncthreads();

    if (w == 0) {            // log-norm final reduction
        float v = sfin[2 * l] + sfin[2 * l + 1];
        v = wave_sum64(v);
        if (l == 0) lognorm[b] = __logf(v) + (float)kacc_sh * LN2F;
    } else if (w == 1) {     // last-tag argmax + serial backtrace
        float a0 = apad[(TT - 1) & 1][padidx(2 * l)];
        float a1 = apad[(TT - 1) & 1][padidx(2 * l + 1)];
        int tag = wave_argmax128(a0, a1, l);
        if (l == 0) {
            tags_lds[TT - 1] = (unsigned char)tag;
            for (int t = TT - 1; t >= 1; --t) {
                tag = bp_lds[t * NN + tag];   // masked rows are identity
                tags_lds[t - 1] = (unsigned char)tag;
            }
        }
    }
    __syncthreads();
    if (tid < TT) outp[(size_t)b * TT + tid] = (float)tags_lds[tid];
}

// Gold-path score + final LL. One block (128 threads) per batch.
__global__ __launch_bounds__(128, 1) void score_kernel(
        const float* __restrict__ em, const int* __restrict__ tags,
        const int* __restrict__ mask, const float* __restrict__ trans,
        const float* __restrict__ lognorm, float* __restrict__ out_ll) {
    const int b = blockIdx.x;
    const int tid = threadIdx.x;
    float acc = 0.f;
    for (int t = tid; t < TT; t += 128) {
        int tg = tags[b * TT + t];
        float mf = (float)mask[b * TT + t];
        acc += em[((size_t)b * TT + t) * NN + tg] * mf;
        if (t >= 1) {
            int tp = tags[b * TT + t - 1];
            acc += trans[tp * NN + tg] * mf;
        }
    }
    acc = wave_sum64(acc);
    __shared__ float rs[2];
    if ((tid & 63) == 0) rs[tid >> 6] = acc;
    __syncthreads();
    if (tid == 0) out_ll[b] = (rs[0] + rs[1]) - lognorm[b];
}

__global__ void copy_trans_kernel(const float* __restrict__ trans,
                                  float* __restrict__ dst) {
    int i = blockIdx.x * 256 + threadIdx.x;
    if (i < NN * NN) dst[i] = trans[i];
}

extern "C" void kernel_launch(void* const* d_in, const int* in_sizes, int n_in,
                              void* d_out, int out_size, void* d_ws, size_t ws_size,
                              hipStream_t stream) {
    const float* em = (const float*)d_in[0];
    const int* tags = (const int*)d_in[1];
    const int* mask = (const int*)d_in[2];
    const float* trans = (const float*)d_in[3];

    float* out = (float*)d_out;
    float* out_ll = out;
    float* out_trans = out + BB;
    float* out_pred = out + BB + NN * NN;

    float* lognorm = (float*)d_ws;   // [256]

    hipLaunchKernelGGL(fwd_kernel, dim3(BB), dim3(1024), 0, stream,
                       em, mask, trans, out_pred, lognorm);
    hipLaunchKernelGGL(copy_trans_kernel, dim3(64), dim3(256), 0, stream,
                       trans, out_trans);
    hipLaunchKernelGGL(score_kernel, dim3(BB), dim3(128), 0, stream,
                       em, tags, mask, trans, lognorm, out_ll);
}